// Round 15
// baseline (167.538 us; speedup 1.0000x reference)
//
#include <hip/hip_runtime.h>

#define F_IN 128
#define H1 32
#define H2 16
#define NPB 128                  // dst-nodes per bucket
#define NBKT 782                 // ceil(100000/128)
#define CAP 4608                 // per-bucket capacity (mean 4092, sigma 64; mean+8sigma)
#define EPT 16                   // edges per thread in bucketize
#define BZB 1024                 // bucketize block size
#define EPB (EPT * BZB)          // 16384 edges per bucketize block
#define RPT 9                    // records per thread in sortbkt (CAP/512 ceil)

typedef __attribute__((ext_vector_type(8))) short bf16x8;
typedef __attribute__((ext_vector_type(4))) float f32x4;

__device__ inline short bf_hi(float f) { return (short)(__float_as_uint(f) >> 16); }
__device__ inline float bf_to_f(short h) {
    return __uint_as_float(((unsigned)(unsigned short)h) << 16);
}
__device__ inline unsigned short bf_rn(float f) {      // round-to-nearest-even bf16
    unsigned u = __float_as_uint(f);
    return (unsigned short)((u + 0x7FFFu + ((u >> 16) & 1u)) >> 16);
}
__device__ inline float blo(unsigned u) { return __uint_as_float(u << 16); }
__device__ inline float bhi(unsigned u) { return __uint_as_float(u & 0xFFFF0000u); }

__global__ void k_initcur(int* bucketCur, int nbkt) {
    int b = blockIdx.x * blockDim.x + threadIdx.x;
    if (b < nbkt) bucketCur[b] = b * CAP;
}

// block-local counting sort into per-bucket capacity regions (dstLocal:7 | src:17)
__global__ __launch_bounds__(1024) void k_bucketize(const int* __restrict__ src,
        const int* __restrict__ dst, int E,
        int* __restrict__ bucketCur, unsigned* __restrict__ packed) {
    __shared__ int lcnt[NBKT + 1];
    __shared__ int lbase[NBKT];
    int t = threadIdx.x;
    for (int b = t; b < NBKT + 1; b += BZB) lcnt[b] = 0;
    __syncthreads();
    int base = blockIdx.x * EPB;
    int eLast = E - 1;
    unsigned val[EPT]; short bk[EPT]; short rk[EPT];
    #pragma unroll
    for (int i = 0; i < EPT; ++i) {
        int e = base + t + i * BZB;
        int ec = e <= eLast ? e : eLast;
        int s = src[ec], d = dst[ec];
        int b = d >> 7;
        bool ok = e <= eLast;
        bk[i] = ok ? (short)b : (short)-1;
        val[i] = ((unsigned)(d & 127) << 17) | (unsigned)s;
        rk[i] = (short)atomicAdd(&lcnt[ok ? b : NBKT], 1);
    }
    __syncthreads();
    for (int b = t; b < NBKT; b += BZB) {
        int c = lcnt[b];
        if (c > 0) lbase[b] = atomicAdd(&bucketCur[b], c);
    }
    __syncthreads();
    #pragma unroll
    for (int i = 0; i < EPT; ++i)
        if (bk[i] >= 0) packed[lbase[bk[i]] + (int)rk[i]] = val[i];
}

// one block per bucket, single pass: rank via one LDS atomic sweep, scan, scatter.
__global__ __launch_bounds__(512) void k_sortbkt(const int* __restrict__ bucketCur,
        const unsigned* __restrict__ packed, unsigned* __restrict__ sorted,
        int* __restrict__ nodeBeg, int* __restrict__ cnt, float* __restrict__ dinv,
        int n) {
    __shared__ int hcnt[NPB];
    __shared__ int hoff[NPB];
    __shared__ int hbase[NPB];
    int b = blockIdx.x, t = threadIdx.x;
    if (t < NPB) hcnt[t] = 0;
    __syncthreads();
    int beg = b * CAP, end = bucketCur[b];
    unsigned recs[RPT]; unsigned short rks[RPT];
    #pragma unroll
    for (int k = 0; k < RPT; ++k) {
        int i = beg + t + k * 512;
        bool ok = i < end;
        int ic = ok ? i : beg;                  // always in-bounds load
        unsigned p = packed[ic];
        recs[k] = ok ? p : 0xFFFFFFFFu;
        rks[k] = 0;
        if (ok) rks[k] = (unsigned short)atomicAdd(&hcnt[p >> 17], 1);
    }
    __syncthreads();
    if (t < NPB) hoff[t] = hcnt[t];
    __syncthreads();
    #pragma unroll
    for (int off = 1; off < NPB; off <<= 1) {
        int x = (t < NPB && t >= off) ? hoff[t - off] : 0;
        __syncthreads();
        if (t < NPB) hoff[t] += x;
        __syncthreads();
    }
    if (t < NPB) {
        int excl = hoff[t] - hcnt[t];
        hbase[t] = excl;
        int v = b * NPB + t;
        if (v < n) {
            nodeBeg[v] = beg + excl;
            cnt[v] = hcnt[t];
            dinv[v] = rsqrtf((float)hcnt[t] + 1.0f);
        }
    }
    __syncthreads();
    #pragma unroll
    for (int k = 0; k < RPT; ++k) {
        if (recs[k] != 0xFFFFFFFFu) {
            int dl = recs[k] >> 17;
            sorted[beg + hbase[dl] + (int)rks[k]] = recs[k] & 0x1FFFF;
        }
    }
}

// MFMA gemm1 (split-bf16 hi/lo), epilogue packs g1 into TWO bf16 feature planes:
// plane p (cols 16p..16p+15) at g1b + p*8n, row = 8 uints.
__global__ __launch_bounds__(256) void k_gemm1(const float* __restrict__ x,
        const float* __restrict__ W1, const float* __restrict__ dinv,
        unsigned* __restrict__ g1b, int n) {
    int wave = threadIdx.x >> 6;
    int lane = threadIdx.x & 63;
    int r = lane & 15, kg = lane >> 4;
    int base = blockIdx.x * 64 + wave * 16;
    int node = base + r;
    bool vnode = node < n;
    int nodec = vnode ? node : (n - 1);

    bf16x8 bh[2][4], bl[2][4];
    #pragma unroll
    for (int jt = 0; jt < 2; ++jt) {
        #pragma unroll
        for (int t = 0; t < 4; ++t) {
            #pragma unroll
            for (int i = 0; i < 8; ++i) {
                float w = W1[(t * 32 + kg * 8 + i) * H1 + jt * 16 + r];
                short h = bf_hi(w);
                bh[jt][t][i] = h;
                bl[jt][t][i] = bf_hi(w - bf_to_f(h));
            }
        }
    }

    bf16x8 ah[4], al[4];
    const float4* x4 = (const float4*)x;
    #pragma unroll
    for (int t = 0; t < 4; ++t) {
        float4 a0 = x4[(size_t)nodec * 32 + t * 8 + kg * 2];
        float4 a1 = x4[(size_t)nodec * 32 + t * 8 + kg * 2 + 1];
        float f[8] = {a0.x, a0.y, a0.z, a0.w, a1.x, a1.y, a1.z, a1.w};
        #pragma unroll
        for (int i = 0; i < 8; ++i) {
            float v = vnode ? f[i] : 0.f;
            short h = bf_hi(v);
            ah[t][i] = h;
            al[t][i] = bf_hi(v - bf_to_f(h));
        }
    }

    f32x4 acc[2] = {{0.f, 0.f, 0.f, 0.f}, {0.f, 0.f, 0.f, 0.f}};
    #pragma unroll
    for (int t = 0; t < 4; ++t) {
        #pragma unroll
        for (int jt = 0; jt < 2; ++jt) {
            acc[jt] = __builtin_amdgcn_mfma_f32_16x16x32_bf16(ah[t], bh[jt][t], acc[jt], 0, 0, 0);
            acc[jt] = __builtin_amdgcn_mfma_f32_16x16x32_bf16(al[t], bh[jt][t], acc[jt], 0, 0, 0);
            acc[jt] = __builtin_amdgcn_mfma_f32_16x16x32_bf16(ah[t], bl[jt][t], acc[jt], 0, 0, 0);
        }
    }

    size_t planeStride = (size_t)n * 8;
    #pragma unroll
    for (int i = 0; i < 4; ++i) {
        int orow = base + kg * 4 + i;             // uniform across the 16 r-lanes
        int oc = orow < n ? orow : 0;
        float dv = dinv[oc];
        float f0 = dv * acc[0][i];                // col r       (plane 0)
        float f1 = dv * acc[1][i];                // col 16+r    (plane 1)
        float p0 = __shfl_xor(f0, 1);             // partner col r^1
        float p1 = __shfl_xor(f1, 1);
        if (orow < n && !(r & 1)) {               // even lane packs (col, col+1)
            g1b[(size_t)orow * 8 + (r >> 1)]               = (unsigned)bf_rn(f0) | ((unsigned)bf_rn(p0) << 16);
            g1b[planeStride + (size_t)orow * 8 + (r >> 1)] = (unsigned)bf_rn(f1) | ((unsigned)bf_rn(p1) << 16);
        }
    }
}

// ONE FEATURE PLANE per launch (3.2 MB table -> L2-resident).
// 2 nodes/wave, 32 lanes/node: 2 jg x 16 edge-slots, 2x unroll (32 edges/body).
__global__ __launch_bounds__(512) void k_agg1(const int* __restrict__ nodeBeg,
        const int* __restrict__ cnt, const unsigned* __restrict__ sorted,
        const unsigned* __restrict__ g1b, const float* __restrict__ dinv,
        const float* __restrict__ b1, float* __restrict__ h1, int n, int plane) {
    int t = threadIdx.x;
    int v = (blockIdx.x * 512 + t) >> 5;     // 32 threads per node
    if (v >= n) return;
    int l = t & 31;
    int jg = l & 1, es = l >> 1;             // 16 edge slots
    int beg = nodeBeg[v], deg = cnt[v];
    const uint4* g4 = (const uint4*)(g1b + (size_t)plane * n * 8);  // row = 2 uint4
    float a0 = 0.f, a1 = 0.f, a2 = 0.f, a3 = 0.f;
    float a4 = 0.f, a5 = 0.f, a6 = 0.f, a7 = 0.f;
    int lastI = deg - 1;
    for (int it = 0; it < deg; it += 32) {
        int i0 = it + es;
        int i1 = it + 16 + es;
        float k0 = i0 <= lastI ? 1.f : 0.f;
        float k1 = i1 <= lastI ? 1.f : 0.f;
        unsigned s0 = sorted[beg + (i0 <= lastI ? i0 : lastI)];
        unsigned s1 = sorted[beg + (i1 <= lastI ? i1 : lastI)];
        uint4 w0 = g4[(size_t)s0 * 2 + jg];
        uint4 w1 = g4[(size_t)s1 * 2 + jg];
        a0 = fmaf(blo(w0.x), k0, a0); a1 = fmaf(bhi(w0.x), k0, a1);
        a2 = fmaf(blo(w0.y), k0, a2); a3 = fmaf(bhi(w0.y), k0, a3);
        a4 = fmaf(blo(w0.z), k0, a4); a5 = fmaf(bhi(w0.z), k0, a5);
        a6 = fmaf(blo(w0.w), k0, a6); a7 = fmaf(bhi(w0.w), k0, a7);
        a0 = fmaf(blo(w1.x), k1, a0); a1 = fmaf(bhi(w1.x), k1, a1);
        a2 = fmaf(blo(w1.y), k1, a2); a3 = fmaf(bhi(w1.y), k1, a3);
        a4 = fmaf(blo(w1.z), k1, a4); a5 = fmaf(bhi(w1.z), k1, a5);
        a6 = fmaf(blo(w1.w), k1, a6); a7 = fmaf(bhi(w1.w), k1, a7);
    }
    #pragma unroll
    for (int m = 2; m < 32; m <<= 1) {       // reduce over es (lane bits 1..4)
        a0 += __shfl_xor(a0, m); a1 += __shfl_xor(a1, m);
        a2 += __shfl_xor(a2, m); a3 += __shfl_xor(a3, m);
        a4 += __shfl_xor(a4, m); a5 += __shfl_xor(a5, m);
        a6 += __shfl_xor(a6, m); a7 += __shfl_xor(a7, m);
    }
    if (es == 0) {                           // l == 0 (jg 0) and l == 1 (jg 1)
        uint4 sw = g4[(size_t)v * 2 + jg];   // self loop, once
        a0 += blo(sw.x); a1 += bhi(sw.x);
        a2 += blo(sw.y); a3 += bhi(sw.y);
        a4 += blo(sw.z); a5 += bhi(sw.z);
        a6 += blo(sw.w); a7 += bhi(sw.w);
        float dv = dinv[v];
        int cb = plane * 4 + jg * 2;         // float4 index of first 4 cols
        float4 bb0 = ((const float4*)b1)[cb];
        float4 bb1 = ((const float4*)b1)[cb + 1];
        float4 r0, r1;
        r0.x = dv * a0 + bb0.x; r0.y = dv * a1 + bb0.y;
        r0.z = dv * a2 + bb0.z; r0.w = dv * a3 + bb0.w;
        r1.x = dv * a4 + bb1.x; r1.y = dv * a5 + bb1.y;
        r1.z = dv * a6 + bb1.z; r1.w = dv * a7 + bb1.w;
        r0.x = r0.x > 0.f ? r0.x : 0.f; r0.y = r0.y > 0.f ? r0.y : 0.f;
        r0.z = r0.z > 0.f ? r0.z : 0.f; r0.w = r0.w > 0.f ? r0.w : 0.f;
        r1.x = r1.x > 0.f ? r1.x : 0.f; r1.y = r1.y > 0.f ? r1.y : 0.f;
        r1.z = r1.z > 0.f ? r1.z : 0.f; r1.w = r1.w > 0.f ? r1.w : 0.f;
        ((float4*)h1)[(size_t)v * 8 + cb]     = r0;
        ((float4*)h1)[(size_t)v * 8 + cb + 1] = r1;
    }
}

// g2b[v,j-pair] = bf16 pack of dinv[v] * sum_k h1[v,k] * W2[k,j]
__global__ void k_gemm2(const float* __restrict__ h1, const float* __restrict__ W2,
                        const float* __restrict__ dinv, unsigned* __restrict__ g2b, int n) {
    __shared__ float Wl[H1 * H2];  // 2 KB
    for (int t = threadIdx.x; t < H1 * H2; t += blockDim.x) Wl[t] = W2[t];
    __syncthreads();
    int idx = blockIdx.x * blockDim.x + threadIdx.x;
    int node = idx >> 4, j = idx & 15;
    float f = 0.f;
    if (node < n) {
        const float* hr = h1 + (size_t)node * H1;
        float s = 0.f;
        #pragma unroll
        for (int k = 0; k < H1; ++k) s += hr[k] * Wl[k * H2 + j];
        f = dinv[node] * s;
    }
    float p = __shfl_down(f, 1);
    if (node < n && !(j & 1))
        g2b[(size_t)node * 8 + (j >> 1)] = (unsigned)bf_rn(f) | ((unsigned)bf_rn(p) << 16);
}

// TWO nodes per wave (32 lanes/node): 2 jg x 16 edge-slots, 2x unroll + fused head.
__global__ __launch_bounds__(512) void k_agg2(const int* __restrict__ nodeBeg,
        const int* __restrict__ cnt, const unsigned* __restrict__ sorted,
        const unsigned* __restrict__ g2b, const float* __restrict__ dinv,
        const float* __restrict__ b2, const float* __restrict__ Wo,
        const float* __restrict__ bo, float* __restrict__ out, int n) {
    int t = threadIdx.x;
    int v = (blockIdx.x * 512 + t) >> 5;     // 32 threads per node
    if (v >= n) return;
    int l = t & 31;
    int jg = l & 1, es = l >> 1;             // 16 edge slots
    int beg = nodeBeg[v], deg = cnt[v];
    const uint4* g4 = (const uint4*)g2b;     // row = 2 uint4
    float a0 = 0.f, a1 = 0.f, a2 = 0.f, a3 = 0.f;
    float a4 = 0.f, a5 = 0.f, a6 = 0.f, a7 = 0.f;
    int lastI = deg - 1;
    for (int it = 0; it < deg; it += 32) {
        int i0 = it + es;
        int i1 = it + 16 + es;
        float k0 = i0 <= lastI ? 1.f : 0.f;
        float k1 = i1 <= lastI ? 1.f : 0.f;
        unsigned s0 = sorted[beg + (i0 <= lastI ? i0 : lastI)];
        unsigned s1 = sorted[beg + (i1 <= lastI ? i1 : lastI)];
        uint4 w0 = g4[(size_t)s0 * 2 + jg];
        uint4 w1 = g4[(size_t)s1 * 2 + jg];
        a0 = fmaf(blo(w0.x), k0, a0); a1 = fmaf(bhi(w0.x), k0, a1);
        a2 = fmaf(blo(w0.y), k0, a2); a3 = fmaf(bhi(w0.y), k0, a3);
        a4 = fmaf(blo(w0.z), k0, a4); a5 = fmaf(bhi(w0.z), k0, a5);
        a6 = fmaf(blo(w0.w), k0, a6); a7 = fmaf(bhi(w0.w), k0, a7);
        a0 = fmaf(blo(w1.x), k1, a0); a1 = fmaf(bhi(w1.x), k1, a1);
        a2 = fmaf(blo(w1.y), k1, a2); a3 = fmaf(bhi(w1.y), k1, a3);
        a4 = fmaf(blo(w1.z), k1, a4); a5 = fmaf(bhi(w1.z), k1, a5);
        a6 = fmaf(blo(w1.w), k1, a6); a7 = fmaf(bhi(w1.w), k1, a7);
    }
    #pragma unroll
    for (int m = 2; m < 32; m <<= 1) {       // reduce over es (lane bits 1..4)
        a0 += __shfl_xor(a0, m); a1 += __shfl_xor(a1, m);
        a2 += __shfl_xor(a2, m); a3 += __shfl_xor(a3, m);
        a4 += __shfl_xor(a4, m); a5 += __shfl_xor(a5, m);
        a6 += __shfl_xor(a6, m); a7 += __shfl_xor(a7, m);
    }
    if (es == 0) {                           // l == 0 (jg 0) and l == 1 (jg 1)
        uint4 sw = g4[(size_t)v * 2 + jg];   // self loop, once
        a0 += blo(sw.x); a1 += bhi(sw.x);
        a2 += blo(sw.y); a3 += bhi(sw.y);
        a4 += blo(sw.z); a5 += bhi(sw.z);
        a6 += blo(sw.w); a7 += bhi(sw.w);
        float dv = dinv[v];
        float4 bb0 = ((const float4*)b2)[jg * 2];
        float4 bb1 = ((const float4*)b2)[jg * 2 + 1];
        float4 ww0 = ((const float4*)Wo)[jg * 2];
        float4 ww1 = ((const float4*)Wo)[jg * 2 + 1];
        float q0 = dv * a0 + bb0.x, q1 = dv * a1 + bb0.y;
        float q2 = dv * a2 + bb0.z, q3 = dv * a3 + bb0.w;
        float q4 = dv * a4 + bb1.x, q5 = dv * a5 + bb1.y;
        float q6 = dv * a6 + bb1.z, q7 = dv * a7 + bb1.w;
        float r = (q0 > 0.f ? q0 : 0.f) * ww0.x
                + (q1 > 0.f ? q1 : 0.f) * ww0.y
                + (q2 > 0.f ? q2 : 0.f) * ww0.z
                + (q3 > 0.f ? q3 : 0.f) * ww0.w
                + (q4 > 0.f ? q4 : 0.f) * ww1.x
                + (q5 > 0.f ? q5 : 0.f) * ww1.y
                + (q6 > 0.f ? q6 : 0.f) * ww1.z
                + (q7 > 0.f ? q7 : 0.f) * ww1.w;
        r += __shfl_xor(r, 1);               // combine jg=0 (l=0) and jg=1 (l=1)
        if (l == 0) out[v] = r + bo[0];
    }
}

extern "C" void kernel_launch(void* const* d_in, const int* in_sizes, int n_in,
                              void* d_out, int out_size, void* d_ws, size_t ws_size,
                              hipStream_t stream) {
    const float* x  = (const float*)d_in[0];
    const int*   ei = (const int*)d_in[1];
    const float* W1 = (const float*)d_in[2];
    const float* b1 = (const float*)d_in[3];
    const float* W2 = (const float*)d_in[4];
    const float* b2 = (const float*)d_in[5];
    const float* Wo = (const float*)d_in[6];
    const float* bo = (const float*)d_in[7];
    float* out = (float*)d_out;

    const int n = in_sizes[0] / F_IN;   // 100000
    const int E = in_sizes[1] / 2;      // 3200000
    const int* src = ei;
    const int* dst = ei + E;
    const int nbkt = (n + NPB - 1) / NPB;  // 782

    auto align = [](size_t s) { return (s + 255) & ~(size_t)255; };
    char* ws = (char*)d_ws;
    size_t o = 0;
    int*      cnt      = (int*)(ws + o); o += align((size_t)n * 4);
    float*    dinv     = (float*)(ws + o); o += align((size_t)n * 4);
    int*      nodeBeg  = (int*)(ws + o); o += align((size_t)n * 4);
    int*      bucketCur= (int*)(ws + o); o += align((size_t)nbkt * 4);
    unsigned* packed   = (unsigned*)(ws + o); o += align((size_t)nbkt * CAP * 4);
    unsigned* sorted   = (unsigned*)(ws + o); o += align((size_t)nbkt * CAP * 4);
    unsigned* g1b      = (unsigned*)(ws + o); o += align((size_t)n * 16 * 4);  // 2 planes x 8n
    float*    h1       = (float*)(ws + o); o += align((size_t)n * H1 * 4);
    unsigned* g2b      = g1b;  // reuse: g1b dead after k_agg1 passes

    const int B = 256;
    const int aggBlocks = (n * 32 + 511) / 512;   // two nodes per wave
    k_initcur  <<<(nbkt + B - 1) / B, B, 0, stream>>>(bucketCur, nbkt);
    k_bucketize<<<(E + EPB - 1) / EPB, BZB, 0, stream>>>(src, dst, E, bucketCur, packed);
    k_sortbkt  <<<nbkt, 512, 0, stream>>>(bucketCur, packed, sorted, nodeBeg, cnt, dinv, n);
    k_gemm1    <<<(n + 63) / 64, 256, 0, stream>>>(x, W1, dinv, g1b, n);
    k_agg1     <<<aggBlocks, 512, 0, stream>>>(nodeBeg, cnt, sorted, g1b, dinv, b1, h1, n, 0);
    k_agg1     <<<aggBlocks, 512, 0, stream>>>(nodeBeg, cnt, sorted, g1b, dinv, b1, h1, n, 1);
    k_gemm2    <<<(n * H2 + B - 1) / B, B, 0, stream>>>(h1, W2, dinv, g2b, n);
    k_agg2     <<<aggBlocks, 512, 0, stream>>>(nodeBeg, cnt, sorted, g2b, dinv, b2, Wo, bo, out, n);
}

// Round 16
// 156.071 us; speedup vs baseline: 1.0735x; 1.0735x over previous
//
#include <hip/hip_runtime.h>

#define F_IN 128
#define H1 32
#define H2 16
#define NPB 128                  // dst-nodes per bucket
#define NBKT 782                 // ceil(100000/128)
#define CAP 4608                 // per-bucket capacity (mean 4092, sigma 64; mean+8sigma)
#define EPT 16                   // edges per thread in bucketize
#define BZB 1024                 // bucketize block size
#define EPB (EPT * BZB)          // 16384 edges per bucketize block
#define RPT 9                    // records per thread in sortbkt (CAP/512 ceil)

typedef __attribute__((ext_vector_type(8))) short bf16x8;
typedef __attribute__((ext_vector_type(4))) float f32x4;

__device__ inline short bf_hi(float f) { return (short)(__float_as_uint(f) >> 16); }
__device__ inline float bf_to_f(short h) {
    return __uint_as_float(((unsigned)(unsigned short)h) << 16);
}
__device__ inline unsigned short bf_rn(float f) {      // round-to-nearest-even bf16
    unsigned u = __float_as_uint(f);
    return (unsigned short)((u + 0x7FFFu + ((u >> 16) & 1u)) >> 16);
}
__device__ inline float blo(unsigned u) { return __uint_as_float(u << 16); }
__device__ inline float bhi(unsigned u) { return __uint_as_float(u & 0xFFFF0000u); }

__global__ void k_initcur(int* bucketCur, int nbkt) {
    int b = blockIdx.x * blockDim.x + threadIdx.x;
    if (b < nbkt) bucketCur[b] = b * CAP;
}

// block-local counting sort into per-bucket capacity regions (dstLocal:7 | src:17)
__global__ __launch_bounds__(1024) void k_bucketize(const int* __restrict__ src,
        const int* __restrict__ dst, int E,
        int* __restrict__ bucketCur, unsigned* __restrict__ packed) {
    __shared__ int lcnt[NBKT + 1];
    __shared__ int lbase[NBKT];
    int t = threadIdx.x;
    for (int b = t; b < NBKT + 1; b += BZB) lcnt[b] = 0;
    __syncthreads();
    int base = blockIdx.x * EPB;
    int eLast = E - 1;
    unsigned val[EPT]; short bk[EPT]; short rk[EPT];
    #pragma unroll
    for (int i = 0; i < EPT; ++i) {
        int e = base + t + i * BZB;
        int ec = e <= eLast ? e : eLast;
        int s = src[ec], d = dst[ec];
        int b = d >> 7;
        bool ok = e <= eLast;
        bk[i] = ok ? (short)b : (short)-1;
        val[i] = ((unsigned)(d & 127) << 17) | (unsigned)s;
        rk[i] = (short)atomicAdd(&lcnt[ok ? b : NBKT], 1);
    }
    __syncthreads();
    for (int b = t; b < NBKT; b += BZB) {
        int c = lcnt[b];
        if (c > 0) lbase[b] = atomicAdd(&bucketCur[b], c);
    }
    __syncthreads();
    #pragma unroll
    for (int i = 0; i < EPT; ++i)
        if (bk[i] >= 0) packed[lbase[bk[i]] + (int)rk[i]] = val[i];
}

// one block per bucket, single pass: rank via one LDS atomic sweep, scan, scatter.
__global__ __launch_bounds__(512) void k_sortbkt(const int* __restrict__ bucketCur,
        const unsigned* __restrict__ packed, unsigned* __restrict__ sorted,
        int* __restrict__ nodeBeg, int* __restrict__ cnt, float* __restrict__ dinv,
        int n) {
    __shared__ int hcnt[NPB];
    __shared__ int hoff[NPB];
    __shared__ int hbase[NPB];
    int b = blockIdx.x, t = threadIdx.x;
    if (t < NPB) hcnt[t] = 0;
    __syncthreads();
    int beg = b * CAP, end = bucketCur[b];
    unsigned recs[RPT]; unsigned short rks[RPT];
    #pragma unroll
    for (int k = 0; k < RPT; ++k) {
        int i = beg + t + k * 512;
        bool ok = i < end;
        int ic = ok ? i : beg;                  // always in-bounds load
        unsigned p = packed[ic];
        recs[k] = ok ? p : 0xFFFFFFFFu;
        rks[k] = 0;
        if (ok) rks[k] = (unsigned short)atomicAdd(&hcnt[p >> 17], 1);
    }
    __syncthreads();
    if (t < NPB) hoff[t] = hcnt[t];
    __syncthreads();
    #pragma unroll
    for (int off = 1; off < NPB; off <<= 1) {
        int x = (t < NPB && t >= off) ? hoff[t - off] : 0;
        __syncthreads();
        if (t < NPB) hoff[t] += x;
        __syncthreads();
    }
    if (t < NPB) {
        int excl = hoff[t] - hcnt[t];
        hbase[t] = excl;
        int v = b * NPB + t;
        if (v < n) {
            nodeBeg[v] = beg + excl;
            cnt[v] = hcnt[t];
            dinv[v] = rsqrtf((float)hcnt[t] + 1.0f);
        }
    }
    __syncthreads();
    #pragma unroll
    for (int k = 0; k < RPT; ++k) {
        if (recs[k] != 0xFFFFFFFFu) {
            int dl = recs[k] >> 17;
            sorted[beg + hbase[dl] + (int)rks[k]] = recs[k] & 0x1FFFF;
        }
    }
}

// MFMA gemm1 (split-bf16 hi/lo), epilogue packs g1 as bf16 pairs -> g1b (16 uints/row)
__global__ __launch_bounds__(256) void k_gemm1(const float* __restrict__ x,
        const float* __restrict__ W1, const float* __restrict__ dinv,
        unsigned* __restrict__ g1b, int n) {
    int wave = threadIdx.x >> 6;
    int lane = threadIdx.x & 63;
    int r = lane & 15, kg = lane >> 4;
    int base = blockIdx.x * 64 + wave * 16;
    int node = base + r;
    bool vnode = node < n;
    int nodec = vnode ? node : (n - 1);

    bf16x8 bh[2][4], bl[2][4];
    #pragma unroll
    for (int jt = 0; jt < 2; ++jt) {
        #pragma unroll
        for (int t = 0; t < 4; ++t) {
            #pragma unroll
            for (int i = 0; i < 8; ++i) {
                float w = W1[(t * 32 + kg * 8 + i) * H1 + jt * 16 + r];
                short h = bf_hi(w);
                bh[jt][t][i] = h;
                bl[jt][t][i] = bf_hi(w - bf_to_f(h));
            }
        }
    }

    bf16x8 ah[4], al[4];
    const float4* x4 = (const float4*)x;
    #pragma unroll
    for (int t = 0; t < 4; ++t) {
        float4 a0 = x4[(size_t)nodec * 32 + t * 8 + kg * 2];
        float4 a1 = x4[(size_t)nodec * 32 + t * 8 + kg * 2 + 1];
        float f[8] = {a0.x, a0.y, a0.z, a0.w, a1.x, a1.y, a1.z, a1.w};
        #pragma unroll
        for (int i = 0; i < 8; ++i) {
            float v = vnode ? f[i] : 0.f;
            short h = bf_hi(v);
            ah[t][i] = h;
            al[t][i] = bf_hi(v - bf_to_f(h));
        }
    }

    f32x4 acc[2] = {{0.f, 0.f, 0.f, 0.f}, {0.f, 0.f, 0.f, 0.f}};
    #pragma unroll
    for (int t = 0; t < 4; ++t) {
        #pragma unroll
        for (int jt = 0; jt < 2; ++jt) {
            acc[jt] = __builtin_amdgcn_mfma_f32_16x16x32_bf16(ah[t], bh[jt][t], acc[jt], 0, 0, 0);
            acc[jt] = __builtin_amdgcn_mfma_f32_16x16x32_bf16(al[t], bh[jt][t], acc[jt], 0, 0, 0);
            acc[jt] = __builtin_amdgcn_mfma_f32_16x16x32_bf16(ah[t], bl[jt][t], acc[jt], 0, 0, 0);
        }
    }

    #pragma unroll
    for (int i = 0; i < 4; ++i) {
        int orow = base + kg * 4 + i;             // uniform across the 16 r-lanes
        int oc = orow < n ? orow : 0;
        float dv = dinv[oc];
        float f0 = dv * acc[0][i];                // col r
        float f1 = dv * acc[1][i];                // col 16+r
        float p0 = __shfl_xor(f0, 1);             // partner col r^1
        float p1 = __shfl_xor(f1, 1);
        if (orow < n && !(r & 1)) {               // even lane packs (col, col+1)
            g1b[(size_t)orow * 16 + (r >> 1)]     = (unsigned)bf_rn(f0) | ((unsigned)bf_rn(p0) << 16);
            g1b[(size_t)orow * 16 + 8 + (r >> 1)] = (unsigned)bf_rn(f1) | ((unsigned)bf_rn(p1) << 16);
        }
    }
}

// one wave per node: uint2 gather (4 bf16 cols/lane), 8 jg x 8 edge-slots, 4x unroll.
// 4 accumulators -> 3-step reduce tree; 4 independent gather chains per body.
__global__ __launch_bounds__(512) void k_agg1(const int* __restrict__ nodeBeg,
        const int* __restrict__ cnt, const unsigned* __restrict__ sorted,
        const unsigned* __restrict__ g1b, const float* __restrict__ dinv,
        const float* __restrict__ b1, float* __restrict__ h1, int n) {
    int t = threadIdx.x;
    int v = (blockIdx.x * 512 + t) >> 6;
    if (v >= n) return;
    int lane = t & 63;
    int jg = lane & 7, es = lane >> 3;   // 8 col-groups (uint2), 8 edge slots
    int beg = nodeBeg[v], deg = cnt[v];
    const uint2* g2v = (const uint2*)g1b;          // row = 8 uint2
    float a0 = 0.f, a1 = 0.f, a2 = 0.f, a3 = 0.f;
    int lastI = deg - 1;
    for (int it = 0; it < deg; it += 32) {
        int i0 = it + es, i1 = it + 8 + es, i2 = it + 16 + es, i3 = it + 24 + es;
        float k0 = i0 <= lastI ? 1.f : 0.f;
        float k1 = i1 <= lastI ? 1.f : 0.f;
        float k2 = i2 <= lastI ? 1.f : 0.f;
        float k3 = i3 <= lastI ? 1.f : 0.f;
        unsigned s0 = sorted[beg + (i0 <= lastI ? i0 : lastI)];
        unsigned s1 = sorted[beg + (i1 <= lastI ? i1 : lastI)];
        unsigned s2 = sorted[beg + (i2 <= lastI ? i2 : lastI)];
        unsigned s3 = sorted[beg + (i3 <= lastI ? i3 : lastI)];
        uint2 w0 = g2v[(size_t)s0 * 8 + jg];
        uint2 w1 = g2v[(size_t)s1 * 8 + jg];
        uint2 w2 = g2v[(size_t)s2 * 8 + jg];
        uint2 w3 = g2v[(size_t)s3 * 8 + jg];
        a0 = fmaf(blo(w0.x), k0, a0); a1 = fmaf(bhi(w0.x), k0, a1);
        a2 = fmaf(blo(w0.y), k0, a2); a3 = fmaf(bhi(w0.y), k0, a3);
        a0 = fmaf(blo(w1.x), k1, a0); a1 = fmaf(bhi(w1.x), k1, a1);
        a2 = fmaf(blo(w1.y), k1, a2); a3 = fmaf(bhi(w1.y), k1, a3);
        a0 = fmaf(blo(w2.x), k2, a0); a1 = fmaf(bhi(w2.x), k2, a1);
        a2 = fmaf(blo(w2.y), k2, a2); a3 = fmaf(bhi(w2.y), k2, a3);
        a0 = fmaf(blo(w3.x), k3, a0); a1 = fmaf(bhi(w3.x), k3, a1);
        a2 = fmaf(blo(w3.y), k3, a2); a3 = fmaf(bhi(w3.y), k3, a3);
    }
    #pragma unroll
    for (int m = 8; m < 64; m <<= 1) {             // reduce over es (lane bits 3..5)
        a0 += __shfl_xor(a0, m); a1 += __shfl_xor(a1, m);
        a2 += __shfl_xor(a2, m); a3 += __shfl_xor(a3, m);
    }
    if (es == 0) {
        uint2 sw = g2v[(size_t)v * 8 + jg];        // self loop, once
        a0 += blo(sw.x); a1 += bhi(sw.x);
        a2 += blo(sw.y); a3 += bhi(sw.y);
        float dv = dinv[v];
        float4 bb = ((const float4*)b1)[jg];       // cols 4jg..4jg+3
        float4 r;
        r.x = dv * a0 + bb.x;
        r.y = dv * a1 + bb.y;
        r.z = dv * a2 + bb.z;
        r.w = dv * a3 + bb.w;
        r.x = r.x > 0.f ? r.x : 0.f;
        r.y = r.y > 0.f ? r.y : 0.f;
        r.z = r.z > 0.f ? r.z : 0.f;
        r.w = r.w > 0.f ? r.w : 0.f;
        ((float4*)h1)[(size_t)v * 8 + jg] = r;
    }
}

// g2b[v,j-pair] = bf16 pack of dinv[v] * sum_k h1[v,k] * W2[k,j]
__global__ void k_gemm2(const float* __restrict__ h1, const float* __restrict__ W2,
                        const float* __restrict__ dinv, unsigned* __restrict__ g2b, int n) {
    __shared__ float Wl[H1 * H2];  // 2 KB
    for (int t = threadIdx.x; t < H1 * H2; t += blockDim.x) Wl[t] = W2[t];
    __syncthreads();
    int idx = blockIdx.x * blockDim.x + threadIdx.x;
    int node = idx >> 4, j = idx & 15;
    float f = 0.f;
    if (node < n) {
        const float* hr = h1 + (size_t)node * H1;
        float s = 0.f;
        #pragma unroll
        for (int k = 0; k < H1; ++k) s += hr[k] * Wl[k * H2 + j];
        f = dinv[node] * s;
    }
    float p = __shfl_down(f, 1);
    if (node < n && !(j & 1))
        g2b[(size_t)node * 8 + (j >> 1)] = (unsigned)bf_rn(f) | ((unsigned)bf_rn(p) << 16);
}

// two nodes per wave (32 lanes/node): uint2 gather, 4 jg x 8 edge-slots, 4x unroll
// + fully fused output head.
__global__ __launch_bounds__(512) void k_agg2(const int* __restrict__ nodeBeg,
        const int* __restrict__ cnt, const unsigned* __restrict__ sorted,
        const unsigned* __restrict__ g2b, const float* __restrict__ dinv,
        const float* __restrict__ b2, const float* __restrict__ Wo,
        const float* __restrict__ bo, float* __restrict__ out, int n) {
    int t = threadIdx.x;
    int v = (blockIdx.x * 512 + t) >> 5;     // 32 threads per node
    if (v >= n) return;
    int l = t & 31;
    int jg = l & 3, es = l >> 2;             // 4 col-groups (uint2), 8 edge slots
    int beg = nodeBeg[v], deg = cnt[v];
    const uint2* g2v = (const uint2*)g2b;    // row = 4 uint2
    float a0 = 0.f, a1 = 0.f, a2 = 0.f, a3 = 0.f;
    int lastI = deg - 1;
    for (int it = 0; it < deg; it += 32) {
        int i0 = it + es, i1 = it + 8 + es, i2 = it + 16 + es, i3 = it + 24 + es;
        float k0 = i0 <= lastI ? 1.f : 0.f;
        float k1 = i1 <= lastI ? 1.f : 0.f;
        float k2 = i2 <= lastI ? 1.f : 0.f;
        float k3 = i3 <= lastI ? 1.f : 0.f;
        unsigned s0 = sorted[beg + (i0 <= lastI ? i0 : lastI)];
        unsigned s1 = sorted[beg + (i1 <= lastI ? i1 : lastI)];
        unsigned s2 = sorted[beg + (i2 <= lastI ? i2 : lastI)];
        unsigned s3 = sorted[beg + (i3 <= lastI ? i3 : lastI)];
        uint2 w0 = g2v[(size_t)s0 * 4 + jg];
        uint2 w1 = g2v[(size_t)s1 * 4 + jg];
        uint2 w2 = g2v[(size_t)s2 * 4 + jg];
        uint2 w3 = g2v[(size_t)s3 * 4 + jg];
        a0 = fmaf(blo(w0.x), k0, a0); a1 = fmaf(bhi(w0.x), k0, a1);
        a2 = fmaf(blo(w0.y), k0, a2); a3 = fmaf(bhi(w0.y), k0, a3);
        a0 = fmaf(blo(w1.x), k1, a0); a1 = fmaf(bhi(w1.x), k1, a1);
        a2 = fmaf(blo(w1.y), k1, a2); a3 = fmaf(bhi(w1.y), k1, a3);
        a0 = fmaf(blo(w2.x), k2, a0); a1 = fmaf(bhi(w2.x), k2, a1);
        a2 = fmaf(blo(w2.y), k2, a2); a3 = fmaf(bhi(w2.y), k2, a3);
        a0 = fmaf(blo(w3.x), k3, a0); a1 = fmaf(bhi(w3.x), k3, a1);
        a2 = fmaf(blo(w3.y), k3, a2); a3 = fmaf(bhi(w3.y), k3, a3);
    }
    #pragma unroll
    for (int m = 4; m < 32; m <<= 1) {       // reduce over es (lane bits 2..4)
        a0 += __shfl_xor(a0, m); a1 += __shfl_xor(a1, m);
        a2 += __shfl_xor(a2, m); a3 += __shfl_xor(a3, m);
    }
    if (es == 0) {                           // lanes l = 0..3 hold jg = 0..3
        uint2 sw = g2v[(size_t)v * 4 + jg];  // self loop, once
        a0 += blo(sw.x); a1 += bhi(sw.x);
        a2 += blo(sw.y); a3 += bhi(sw.y);
        float dv = dinv[v];
        float4 bb = ((const float4*)b2)[jg];
        float4 ww = ((const float4*)Wo)[jg];
        float q0 = dv * a0 + bb.x;
        float q1 = dv * a1 + bb.y;
        float q2 = dv * a2 + bb.z;
        float q3 = dv * a3 + bb.w;
        float r = (q0 > 0.f ? q0 : 0.f) * ww.x
                + (q1 > 0.f ? q1 : 0.f) * ww.y
                + (q2 > 0.f ? q2 : 0.f) * ww.z
                + (q3 > 0.f ? q3 : 0.f) * ww.w;
        r += __shfl_xor(r, 1);
        r += __shfl_xor(r, 2);
        if (l == 0) out[v] = r + bo[0];
    }
}

extern "C" void kernel_launch(void* const* d_in, const int* in_sizes, int n_in,
                              void* d_out, int out_size, void* d_ws, size_t ws_size,
                              hipStream_t stream) {
    const float* x  = (const float*)d_in[0];
    const int*   ei = (const int*)d_in[1];
    const float* W1 = (const float*)d_in[2];
    const float* b1 = (const float*)d_in[3];
    const float* W2 = (const float*)d_in[4];
    const float* b2 = (const float*)d_in[5];
    const float* Wo = (const float*)d_in[6];
    const float* bo = (const float*)d_in[7];
    float* out = (float*)d_out;

    const int n = in_sizes[0] / F_IN;   // 100000
    const int E = in_sizes[1] / 2;      // 3200000
    const int* src = ei;
    const int* dst = ei + E;
    const int nbkt = (n + NPB - 1) / NPB;  // 782

    auto align = [](size_t s) { return (s + 255) & ~(size_t)255; };
    char* ws = (char*)d_ws;
    size_t o = 0;
    int*      cnt      = (int*)(ws + o); o += align((size_t)n * 4);
    float*    dinv     = (float*)(ws + o); o += align((size_t)n * 4);
    int*      nodeBeg  = (int*)(ws + o); o += align((size_t)n * 4);
    int*      bucketCur= (int*)(ws + o); o += align((size_t)nbkt * 4);
    unsigned* packed   = (unsigned*)(ws + o); o += align((size_t)nbkt * CAP * 4);
    unsigned* sorted   = (unsigned*)(ws + o); o += align((size_t)nbkt * CAP * 4);
    unsigned* g1b      = (unsigned*)(ws + o); o += align((size_t)n * 16 * 4);
    float*    h1       = (float*)(ws + o); o += align((size_t)n * H1 * 4);
    unsigned* g2b      = g1b;  // reuse: g1b dead after k_agg1 (needs 8n <= 16n uints)

    const int B = 256;
    const int agg1Blocks = (n * 64 + 511) / 512;  // one wave per node
    const int agg2Blocks = (n * 32 + 511) / 512;  // two nodes per wave
    k_initcur  <<<(nbkt + B - 1) / B, B, 0, stream>>>(bucketCur, nbkt);
    k_bucketize<<<(E + EPB - 1) / EPB, BZB, 0, stream>>>(src, dst, E, bucketCur, packed);
    k_sortbkt  <<<nbkt, 512, 0, stream>>>(bucketCur, packed, sorted, nodeBeg, cnt, dinv, n);
    k_gemm1    <<<(n + 63) / 64, 256, 0, stream>>>(x, W1, dinv, g1b, n);
    k_agg1     <<<agg1Blocks, 512, 0, stream>>>(nodeBeg, cnt, sorted, g1b, dinv, b1, h1, n);
    k_gemm2    <<<(n * H2 + B - 1) / B, B, 0, stream>>>(h1, W2, dinv, g2b, n);
    k_agg2     <<<agg2Blocks, 512, 0, stream>>>(nodeBeg, cnt, sorted, g2b, dinv, b2, Wo, bo, out, n);
}